// Round 7
// baseline (223.329 us; speedup 1.0000x reference)
//
#include <hip/hip_runtime.h>
#include <hip/hip_bf16.h>

#define N_NODES 50000
#define N_EDGES 800000

constexpr int NP = 50176;       // N_NODES padded to 256
constexpr int E4 = N_EDGES / 4;                    // 200000
constexpr int EB4 = (E4 + 255) / 256;              // 782 blocks, 4 edges/thread
constexpr int WCB = 256;                           // 65536 wcat elements / 256
constexpr int CVB = (N_NODES * 128 / 4 + 255) / 256;   // 6250 cvt blocks

typedef __attribute__((ext_vector_type(8))) short bf16x8;
typedef __attribute__((ext_vector_type(4))) float f32x4;

__device__ __forceinline__ unsigned short f2bf(float f) {
    unsigned u = __float_as_uint(f);
    u += 0x7FFFu + ((u >> 16) & 1u);   // round-nearest-even
    return (unsigned short)(u >> 16);
}

// ---------------- zero counters (rocclr fillBuffer has ~40us fixed cost) ----------------
__global__ void zero_kernel(int* __restrict__ p, int n) {
    int i = blockIdx.x * 256 + threadIdx.x;
    if (i < n) p[i] = 0;
}

// ---------------- fused prep: edge count (ILP-4, 2-replica atomics) + Wcat + x->bf16 ----------------
__global__ __launch_bounds__(256) void prep_kernel(
        const int* __restrict__ dst, int* __restrict__ cnt0, int* __restrict__ cnt1,
        int* __restrict__ pos,
        const float* __restrict__ W1l, const float* __restrict__ W1r,
        const float* __restrict__ W2l, const float* __restrict__ W2r,
        const float* __restrict__ W3l, const float* __restrict__ W3r,
        unsigned short* __restrict__ Wc1, unsigned short* __restrict__ Wc2,
        unsigned short* __restrict__ Wc3,
        const float* __restrict__ x, unsigned short* __restrict__ xb) {
    int b = blockIdx.x;
    int tid = threadIdx.x;
    if (b < EB4) {
        // 4 edges/thread: 4 independent returning atomics in flight; even edges ->
        // cnt0, odd -> cnt1 (halves per-line contention)
        int t4 = b * 256 + tid;
        if (t4 < E4) {
            int4 d4 = reinterpret_cast<const int4*>(dst)[t4];
            int4 p4;
            p4.x = atomicAdd(&cnt0[d4.x], 1);
            p4.y = atomicAdd(&cnt1[d4.y], 1);
            p4.z = atomicAdd(&cnt0[d4.z], 1);
            p4.w = atomicAdd(&cnt1[d4.w], 1);
            reinterpret_cast<int4*>(pos)[t4] = p4;
        }
    } else if (b < EB4 + WCB) {
        // Wcat[n][k] = bf16( k<din ? Wl[n][k] : Wr[n][k-din] )  -- B^T layout for MFMA
        int idx = (b - EB4) * 256 + tid;   // [0, 65536)
        if (idx < 32768) {
            int nr = idx >> 8, k = idx & 255;
            float v = (k < 128) ? W1l[nr * 128 + k] : W1r[nr * 128 + (k - 128)];
            Wc1[idx] = f2bf(v);
        } else if (idx < 49152) {
            int j = idx - 32768;
            int nr = j >> 8, k = j & 255;
            float v = (k < 128) ? W2l[nr * 128 + k] : W2r[nr * 128 + (k - 128)];
            Wc2[j] = f2bf(v);
        } else {
            int j = idx - 49152;
            int nr = j >> 7, k = j & 127;
            float v = (k < 64) ? W3l[nr * 64 + k] : W3r[nr * 64 + (k - 64)];
            Wc3[j] = f2bf(v);
        }
    } else {
        // x (f32) -> bf16 dense, 4 elems/thread
        int i = (b - EB4 - WCB) * 256 + tid;
        if (i < N_NODES * 128 / 4) {
            float4 v = reinterpret_cast<const float4*>(x)[i];
            uint2 p;
            p.x = (unsigned)f2bf(v.x) | ((unsigned)f2bf(v.y) << 16);
            p.y = (unsigned)f2bf(v.z) | ((unsigned)f2bf(v.w) << 16);
            reinterpret_cast<uint2*>(xb)[i] = p;
        }
    }
}

// scan over cnt0+cnt1; writes total count (for agg), row_ptr, inv_deg
__global__ void assign_kernel(const int* __restrict__ cnt0, const int* __restrict__ cnt1,
                              int* __restrict__ cnt_tot, int* __restrict__ row_ptr,
                              float* __restrict__ inv_deg, int* __restrict__ total, int n) {
    int i = blockIdx.x * blockDim.x + threadIdx.x;
    int lane = threadIdx.x & 63;
    int v = (i < n) ? (cnt0[i] + cnt1[i]) : 0;
    if (i < n) cnt_tot[i] = v;
    int s = v;
    #pragma unroll
    for (int off = 1; off < 64; off <<= 1) {
        int t = __shfl_up(s, off);
        if (lane >= off) s += t;
    }
    int base = 0;
    if (lane == 63) base = atomicAdd(total, s);
    base = __shfl(base, 63);
    if (i < n) {
        row_ptr[i] = base + s - v;
        inv_deg[i] = 1.0f / (float)(v > 1 ? v : 1);
    }
}

// atomic-free scatter, 4 edges/thread; odd edges offset by cnt0[d]
__global__ void fill_kernel(const int* __restrict__ src, const int* __restrict__ dst,
                            const int* __restrict__ row_ptr, const int* __restrict__ cnt0,
                            const int* __restrict__ pos, int* __restrict__ edge_src) {
    int t4 = blockIdx.x * 256 + threadIdx.x;
    if (t4 < E4) {
        int4 s4 = reinterpret_cast<const int4*>(src)[t4];
        int4 d4 = reinterpret_cast<const int4*>(dst)[t4];
        int4 p4 = reinterpret_cast<const int4*>(pos)[t4];
        edge_src[row_ptr[d4.x] + p4.x] = s4.x;
        edge_src[row_ptr[d4.y] + cnt0[d4.y] + p4.y] = s4.y;
        edge_src[row_ptr[d4.z] + p4.z] = s4.z;
        edge_src[row_ptr[d4.w] + cnt0[d4.w] + p4.w] = s4.w;
    }
}

// ---------------- mean aggregation: one wave per node, bf16 gather, bf16 mean out ----------------
template<int D>
__global__ __launch_bounds__(256) void agg_kernel(
        const unsigned short* __restrict__ hb,
        const int* __restrict__ row_ptr, const int* __restrict__ cnt,
        const int* __restrict__ edge_src,
        const float* __restrict__ inv_deg, unsigned short* __restrict__ meanb, int n) {
    constexpr int LPR = D / 8;
    constexpr int EPW = 64 / LPR;
    int wid = (blockIdx.x * 256 + threadIdx.x) >> 6;
    int lane = threadIdx.x & 63;
    if (wid >= n) return;
    int beg = row_ptr[wid];
    int end = beg + cnt[wid];
    float inv = inv_deg[wid];
    int sub = lane / LPR;
    int li = lane % LPR;

    float acc[8];
    #pragma unroll
    for (int j = 0; j < 8; ++j) acc[j] = 0.f;

    for (int e0 = beg; e0 < end; e0 += 2 * EPW) {
        int e = e0 + sub;
        int e2 = e + EPW;
        uint4 v0 = {0u, 0u, 0u, 0u}, v1 = {0u, 0u, 0u, 0u};
        if (e < end) {
            int s0 = edge_src[e];
            v0 = *reinterpret_cast<const uint4*>(hb + (size_t)s0 * D + li * 8);
        }
        if (e2 < end) {
            int s1 = edge_src[e2];
            v1 = *reinterpret_cast<const uint4*>(hb + (size_t)s1 * D + li * 8);
        }
        unsigned w;
        #define ACCW(u, j0) w = (u); acc[j0] += __uint_as_float(w << 16); acc[j0+1] += __uint_as_float(w & 0xFFFF0000u)
        ACCW(v0.x, 0); ACCW(v0.y, 2); ACCW(v0.z, 4); ACCW(v0.w, 6);
        ACCW(v1.x, 0); ACCW(v1.y, 2); ACCW(v1.z, 4); ACCW(v1.w, 6);
        #undef ACCW
    }
    #pragma unroll
    for (int off = LPR; off < 64; off <<= 1) {
        #pragma unroll
        for (int j = 0; j < 8; ++j) acc[j] += __shfl_xor(acc[j], off);
    }
    if (lane < LPR) {
        uint4 w;
        w.x = (unsigned)f2bf(acc[0] * inv) | ((unsigned)f2bf(acc[1] * inv) << 16);
        w.y = (unsigned)f2bf(acc[2] * inv) | ((unsigned)f2bf(acc[3] * inv) << 16);
        w.z = (unsigned)f2bf(acc[4] * inv) | ((unsigned)f2bf(acc[5] * inv) << 16);
        w.w = (unsigned)f2bf(acc[6] * inv) | ((unsigned)f2bf(acc[7] * inv) << 16);
        *reinterpret_cast<uint4*>(meanb + (size_t)wid * D + li * 8) = w;
    }
}

// ---------------- MFMA GEMM v3: B-in-registers, M-loop per wave ----------------
template<int K, int DOUT, bool WB>
__global__ __launch_bounds__(256, 3) void mfma_gemm_kernel(
        const unsigned short* __restrict__ Ab,
        const unsigned short* __restrict__ Fb,
        const unsigned short* __restrict__ Wc,
        const float* __restrict__ bias,
        float* __restrict__ out, int outs,
        unsigned short* __restrict__ outb, int n) {
    constexpr int DIN = K / 2;
    constexpr int KK = K / 32;
    constexpr int NWC = DOUT / 32;
    constexpr int NWM = 4 / NWC;
    constexpr int GW = 4;
    constexpr int BM = 16 * GW * NWM;
    int wave = threadIdx.x >> 6;
    int lane = threadIdx.x & 63;
    int wc = wave % NWC;
    int wm = wave / NWC;
    int arow = lane & 15;
    int kseg = lane >> 4;

    bf16x8 b0[KK], b1[KK];
    {
        const unsigned short* wp0 = Wc + (size_t)(wc * 32 + arow) * K + kseg * 8;
        const unsigned short* wp1 = wp0 + (size_t)16 * K;
        #pragma unroll
        for (int kk = 0; kk < KK; ++kk) {
            b0[kk] = *reinterpret_cast<const bf16x8*>(wp0 + kk * 32);
            b1[kk] = *reinterpret_cast<const bf16x8*>(wp1 + kk * 32);
        }
    }
    float bv0 = bias[wc * 32 + arow];
    float bv1 = bias[wc * 32 + 16 + arow];

    int g0 = blockIdx.x * (BM / 16) + wm * GW;

    bf16x8 a0[KK], a1[KK];

    #define LOADA(g, dst)                                                          \
    {                                                                              \
        int node = (g0 + (g)) * 16 + arow;                                         \
        int ncl = node < n ? node : 0;                                             \
        _Pragma("unroll")                                                          \
        for (int kk = 0; kk < KK; ++kk) {                                          \
            int k = kk * 32 + kseg * 8;                                            \
            const unsigned short* p = (k < DIN) ? (Ab + (size_t)ncl * DIN + k)     \
                                                : (Fb + (size_t)ncl * DIN + (k - DIN)); \
            dst[kk] = *reinterpret_cast<const bf16x8*>(p);                         \
        }                                                                          \
    }

    #define COMPUTE(g, ab)                                                         \
    {                                                                              \
        f32x4 acc0 = {0.f, 0.f, 0.f, 0.f}, acc1 = {0.f, 0.f, 0.f, 0.f};           \
        _Pragma("unroll")                                                          \
        for (int kk = 0; kk < KK; ++kk) {                                          \
            acc0 = __builtin_amdgcn_mfma_f32_16x16x32_bf16(ab[kk], b0[kk], acc0, 0, 0, 0); \
            acc1 = __builtin_amdgcn_mfma_f32_16x16x32_bf16(ab[kk], b1[kk], acc1, 0, 0, 0); \
        }                                                                          \
        int gbase = (g0 + (g)) * 16 + kseg * 4;                                    \
        _Pragma("unroll")                                                          \
        for (int r = 0; r < 4; ++r) {                                              \
            int gn = gbase + r;                                                    \
            if (gn < n) {                                                          \
                int col0 = wc * 32 + arow;                                         \
                float v0 = fmaxf(acc0[r] + bv0, 0.f);                              \
                float v1 = fmaxf(acc1[r] + bv1, 0.f);                              \
                out[(size_t)gn * outs + col0] = v0;                                \
                out[(size_t)gn * outs + col0 + 16] = v1;                           \
                if constexpr (WB) {                                                \
                    outb[(size_t)gn * DOUT + col0] = f2bf(v0);                     \
                    outb[(size_t)gn * DOUT + col0 + 16] = f2bf(v1);                \
                }                                                                  \
            }                                                                      \
        }                                                                          \
    }

    LOADA(0, a0);
    #pragma unroll
    for (int gp = 0; gp < GW; gp += 2) {
        LOADA(gp + 1, a1);
        COMPUTE(gp, a0);
        if (gp + 2 < GW) LOADA(gp + 2, a0);
        COMPUTE(gp + 1, a1);
    }
    #undef LOADA
    #undef COMPUTE
}

extern "C" void kernel_launch(void* const* d_in, const int* in_sizes, int n_in,
                              void* d_out, int out_size, void* d_ws, size_t ws_size,
                              hipStream_t stream) {
    const float* x   = (const float*)d_in[0];
    const int*   ei  = (const int*)d_in[1];
    const float* W1l = (const float*)d_in[2];
    const float* b1  = (const float*)d_in[3];
    const float* W1r = (const float*)d_in[4];
    const float* W2l = (const float*)d_in[5];
    const float* b2  = (const float*)d_in[6];
    const float* W2r = (const float*)d_in[7];
    const float* W3l = (const float*)d_in[8];
    const float* b3  = (const float*)d_in[9];
    const float* W3r = (const float*)d_in[10];
    float* out = (float*)d_out;

    const int* src = ei;
    const int* dst = ei + N_EDGES;

    int* wsi = (int*)d_ws;
    int*   cnt0     = wsi;                    // NP
    int*   cnt1     = wsi + NP;               // NP
    int*   total    = wsi + 2 * NP;           // 64
    int*   cnt_tot  = wsi + 2 * NP + 64;      // NP
    int*   row_ptr  = wsi + 3 * NP + 64;      // NP
    float* inv_deg  = (float*)(wsi + 4 * NP + 64);
    int*   edge_src = wsi + 5 * NP + 64;      // E
    int*   pos      = edge_src + N_EDGES;     // E
    unsigned short* Wc1 = (unsigned short*)(pos + N_EDGES);       // 128*256
    unsigned short* Wc2 = Wc1 + 128 * 256;                        // 64*256
    unsigned short* Wc3 = Wc2 + 64 * 256;                         // 128*128
    unsigned short* meanb = Wc3 + 128 * 128;                      // N*128 bf16
    unsigned short* xb  = meanb + (size_t)N_NODES * 128;          // N*128 bf16
    unsigned short* h1b = xb + (size_t)N_NODES * 128;             // N*128 bf16
    unsigned short* h2b = h1b + (size_t)N_NODES * 128;            // N*64  bf16

    // zero cnt0+cnt1+total with our own kernel
    zero_kernel<<<(2 * NP + 64 + 255) / 256, 256, 0, stream>>>(cnt0, 2 * NP + 64);

    prep_kernel<<<EB4 + WCB + CVB, 256, 0, stream>>>(dst, cnt0, cnt1, pos,
        W1l, W1r, W2l, W2r, W3l, W3r, Wc1, Wc2, Wc3, x, xb);

    assign_kernel<<<NP / 256, 256, 0, stream>>>(cnt0, cnt1, cnt_tot, row_ptr, inv_deg, total, N_NODES);
    fill_kernel<<<EB4, 256, 0, stream>>>(src, dst, row_ptr, cnt0, pos, edge_src);

    const int AGG_BLOCKS = (N_NODES + 3) / 4;
    const int GB64  = (N_NODES + 63) / 64;     // 782
    const int GB128 = (N_NODES + 127) / 128;   // 391

    // layer 1
    agg_kernel<128><<<AGG_BLOCKS, 256, 0, stream>>>(xb, row_ptr, cnt_tot, edge_src, inv_deg, meanb, N_NODES);
    mfma_gemm_kernel<256, 128, true><<<GB64, 256, 0, stream>>>(meanb, xb, Wc1, b1, out, 320, h1b, N_NODES);

    // layer 2
    agg_kernel<128><<<AGG_BLOCKS, 256, 0, stream>>>(h1b, row_ptr, cnt_tot, edge_src, inv_deg, meanb, N_NODES);
    mfma_gemm_kernel<256, 64, true><<<GB128, 256, 0, stream>>>(meanb, h1b, Wc2, b2, out + 128, 320, h2b, N_NODES);

    // layer 3
    agg_kernel<64><<<AGG_BLOCKS, 256, 0, stream>>>(h2b, row_ptr, cnt_tot, edge_src, inv_deg, meanb, N_NODES);
    mfma_gemm_kernel<128, 128, false><<<GB64, 256, 0, stream>>>(meanb, h2b, Wc3, b3, out + 192, 320, nullptr, N_NODES);
}

// Round 8
// 221.305 us; speedup vs baseline: 1.0091x; 1.0091x over previous
//
#include <hip/hip_runtime.h>
#include <hip/hip_bf16.h>

#define N_NODES 50000
#define N_EDGES 800000

constexpr int NP = 50176;       // N_NODES padded to 256
constexpr int E4 = N_EDGES / 4;                    // 200000
constexpr int EB4 = (E4 + 255) / 256;              // 782 blocks, 4 edges/thread
constexpr int WCB = 256;                           // 65536 wcat elements / 256
constexpr int CVB = (N_NODES * 128 / 4 + 255) / 256;   // 6250 cvt blocks

typedef __attribute__((ext_vector_type(8))) short bf16x8;
typedef __attribute__((ext_vector_type(4))) float f32x4;

__device__ __forceinline__ unsigned short f2bf(float f) {
    unsigned u = __float_as_uint(f);
    u += 0x7FFFu + ((u >> 16) & 1u);   // round-nearest-even
    return (unsigned short)(u >> 16);
}

// ---------------- zero counters (rocclr fillBuffer has ~40us fixed cost) ----------------
__global__ void zero_kernel(int* __restrict__ p, int n) {
    int i = blockIdx.x * 256 + threadIdx.x;
    if (i < n) p[i] = 0;
}

// ---------------- fused prep: edge count + Wcat + x->bf16 ----------------
// NOTE (R7 post-mortem): 800k returning device-atomics are a fixed ~40us wall;
// ILP-4 and 2-replica counters were both null -> atomic THROUGHPUT bound at the
// coherence point. Keep simple; overlap independent work under the wall.
__global__ __launch_bounds__(256) void prep_kernel(
        const int* __restrict__ dst, int* __restrict__ cnt, int* __restrict__ pos,
        const float* __restrict__ W1l, const float* __restrict__ W1r,
        const float* __restrict__ W2l, const float* __restrict__ W2r,
        const float* __restrict__ W3l, const float* __restrict__ W3r,
        unsigned short* __restrict__ Wc1, unsigned short* __restrict__ Wc2,
        unsigned short* __restrict__ Wc3,
        const float* __restrict__ x, unsigned short* __restrict__ xb) {
    int b = blockIdx.x;
    int tid = threadIdx.x;
    if (b < EB4) {
        int t4 = b * 256 + tid;
        if (t4 < E4) {
            int4 d4 = reinterpret_cast<const int4*>(dst)[t4];
            int4 p4;
            p4.x = atomicAdd(&cnt[d4.x], 1);
            p4.y = atomicAdd(&cnt[d4.y], 1);
            p4.z = atomicAdd(&cnt[d4.z], 1);
            p4.w = atomicAdd(&cnt[d4.w], 1);
            reinterpret_cast<int4*>(pos)[t4] = p4;
        }
    } else if (b < EB4 + WCB) {
        // Wcat[n][k] = bf16( k<din ? Wl[n][k] : Wr[n][k-din] )  -- B^T layout for MFMA
        int idx = (b - EB4) * 256 + tid;   // [0, 65536)
        if (idx < 32768) {
            int nr = idx >> 8, k = idx & 255;
            float v = (k < 128) ? W1l[nr * 128 + k] : W1r[nr * 128 + (k - 128)];
            Wc1[idx] = f2bf(v);
        } else if (idx < 49152) {
            int j = idx - 32768;
            int nr = j >> 8, k = j & 255;
            float v = (k < 128) ? W2l[nr * 128 + k] : W2r[nr * 128 + (k - 128)];
            Wc2[j] = f2bf(v);
        } else {
            int j = idx - 49152;
            int nr = j >> 7, k = j & 127;
            float v = (k < 64) ? W3l[nr * 64 + k] : W3r[nr * 64 + (k - 64)];
            Wc3[j] = f2bf(v);
        }
    } else {
        // x (f32) -> bf16 dense, 4 elems/thread
        int i = (b - EB4 - WCB) * 256 + tid;
        if (i < N_NODES * 128 / 4) {
            float4 v = reinterpret_cast<const float4*>(x)[i];
            uint2 p;
            p.x = (unsigned)f2bf(v.x) | ((unsigned)f2bf(v.y) << 16);
            p.y = (unsigned)f2bf(v.z) | ((unsigned)f2bf(v.w) << 16);
            reinterpret_cast<uint2*>(xb)[i] = p;
        }
    }
}

__global__ void assign_kernel(const int* __restrict__ cnt, int* __restrict__ row_ptr,
                              float* __restrict__ inv_deg, int* __restrict__ total, int n) {
    int i = blockIdx.x * blockDim.x + threadIdx.x;
    int lane = threadIdx.x & 63;
    int v = (i < n) ? cnt[i] : 0;
    int s = v;
    #pragma unroll
    for (int off = 1; off < 64; off <<= 1) {
        int t = __shfl_up(s, off);
        if (lane >= off) s += t;
    }
    int base = 0;
    if (lane == 63) base = atomicAdd(total, s);
    base = __shfl(base, 63);
    if (i < n) {
        row_ptr[i] = base + s - v;
        inv_deg[i] = 1.0f / (float)(v > 1 ? v : 1);
    }
}

// atomic-free scatter, 4 edges/thread
__global__ void fill_kernel(const int* __restrict__ src, const int* __restrict__ dst,
                            const int* __restrict__ row_ptr,
                            const int* __restrict__ pos, int* __restrict__ edge_src) {
    int t4 = blockIdx.x * 256 + threadIdx.x;
    if (t4 < E4) {
        int4 s4 = reinterpret_cast<const int4*>(src)[t4];
        int4 d4 = reinterpret_cast<const int4*>(dst)[t4];
        int4 p4 = reinterpret_cast<const int4*>(pos)[t4];
        edge_src[row_ptr[d4.x] + p4.x] = s4.x;
        edge_src[row_ptr[d4.y] + p4.y] = s4.y;
        edge_src[row_ptr[d4.z] + p4.z] = s4.z;
        edge_src[row_ptr[d4.w] + p4.w] = s4.w;
    }
}

// ---------------- mean aggregation: one wave per node, ILP-4 bf16 gathers ----------------
// D/8 lanes per row; EPW=64/LPR edge sub-groups; 4 edges in flight per lane.
// deg ~Poisson(16) -> most nodes finish in ONE unrolled iteration.
template<int D>
__global__ __launch_bounds__(256) void agg_kernel(
        const unsigned short* __restrict__ hb,
        const int* __restrict__ row_ptr, const int* __restrict__ cnt,
        const int* __restrict__ edge_src,
        const float* __restrict__ inv_deg, unsigned short* __restrict__ meanb, int n) {
    constexpr int LPR = D / 8;
    constexpr int EPW = 64 / LPR;
    int wid = (blockIdx.x * 256 + threadIdx.x) >> 6;
    int lane = threadIdx.x & 63;
    if (wid >= n) return;
    int beg = row_ptr[wid];
    int end = beg + cnt[wid];
    float inv = inv_deg[wid];
    int sub = lane / LPR;
    int li = lane % LPR;

    float acc[8];
    #pragma unroll
    for (int j = 0; j < 8; ++j) acc[j] = 0.f;

    for (int e0 = beg; e0 < end; e0 += 4 * EPW) {
        int ea = e0 + sub;
        int eb = ea + EPW;
        int ec = ea + 2 * EPW;
        int ed = ea + 3 * EPW;
        uint4 v0 = {0u,0u,0u,0u}, v1 = {0u,0u,0u,0u}, v2 = {0u,0u,0u,0u}, v3 = {0u,0u,0u,0u};
        if (ea < end) v0 = *reinterpret_cast<const uint4*>(hb + (size_t)edge_src[ea] * D + li * 8);
        if (eb < end) v1 = *reinterpret_cast<const uint4*>(hb + (size_t)edge_src[eb] * D + li * 8);
        if (ec < end) v2 = *reinterpret_cast<const uint4*>(hb + (size_t)edge_src[ec] * D + li * 8);
        if (ed < end) v3 = *reinterpret_cast<const uint4*>(hb + (size_t)edge_src[ed] * D + li * 8);
        unsigned w;
        #define ACCW(u, j0) w = (u); acc[j0] += __uint_as_float(w << 16); acc[j0+1] += __uint_as_float(w & 0xFFFF0000u)
        ACCW(v0.x, 0); ACCW(v0.y, 2); ACCW(v0.z, 4); ACCW(v0.w, 6);
        ACCW(v1.x, 0); ACCW(v1.y, 2); ACCW(v1.z, 4); ACCW(v1.w, 6);
        ACCW(v2.x, 0); ACCW(v2.y, 2); ACCW(v2.z, 4); ACCW(v2.w, 6);
        ACCW(v3.x, 0); ACCW(v3.y, 2); ACCW(v3.z, 4); ACCW(v3.w, 6);
        #undef ACCW
    }
    #pragma unroll
    for (int off = LPR; off < 64; off <<= 1) {
        #pragma unroll
        for (int j = 0; j < 8; ++j) acc[j] += __shfl_xor(acc[j], off);
    }
    if (lane < LPR) {
        uint4 w;
        w.x = (unsigned)f2bf(acc[0] * inv) | ((unsigned)f2bf(acc[1] * inv) << 16);
        w.y = (unsigned)f2bf(acc[2] * inv) | ((unsigned)f2bf(acc[3] * inv) << 16);
        w.z = (unsigned)f2bf(acc[4] * inv) | ((unsigned)f2bf(acc[5] * inv) << 16);
        w.w = (unsigned)f2bf(acc[6] * inv) | ((unsigned)f2bf(acc[7] * inv) << 16);
        *reinterpret_cast<uint4*>(meanb + (size_t)wid * D + li * 8) = w;
    }
}

// ---------------- MFMA GEMM v3: B-in-registers, M-loop per wave ----------------
template<int K, int DOUT, bool WB>
__global__ __launch_bounds__(256, 3) void mfma_gemm_kernel(
        const unsigned short* __restrict__ Ab,
        const unsigned short* __restrict__ Fb,
        const unsigned short* __restrict__ Wc,
        const float* __restrict__ bias,
        float* __restrict__ out, int outs,
        unsigned short* __restrict__ outb, int n) {
    constexpr int DIN = K / 2;
    constexpr int KK = K / 32;
    constexpr int NWC = DOUT / 32;
    constexpr int NWM = 4 / NWC;
    constexpr int GW = 4;
    constexpr int BM = 16 * GW * NWM;
    int wave = threadIdx.x >> 6;
    int lane = threadIdx.x & 63;
    int wc = wave % NWC;
    int wm = wave / NWC;
    int arow = lane & 15;
    int kseg = lane >> 4;

    bf16x8 b0[KK], b1[KK];
    {
        const unsigned short* wp0 = Wc + (size_t)(wc * 32 + arow) * K + kseg * 8;
        const unsigned short* wp1 = wp0 + (size_t)16 * K;
        #pragma unroll
        for (int kk = 0; kk < KK; ++kk) {
            b0[kk] = *reinterpret_cast<const bf16x8*>(wp0 + kk * 32);
            b1[kk] = *reinterpret_cast<const bf16x8*>(wp1 + kk * 32);
        }
    }
    float bv0 = bias[wc * 32 + arow];
    float bv1 = bias[wc * 32 + 16 + arow];

    int g0 = blockIdx.x * (BM / 16) + wm * GW;

    bf16x8 a0[KK], a1[KK];

    #define LOADA(g, dst)                                                          \
    {                                                                              \
        int node = (g0 + (g)) * 16 + arow;                                         \
        int ncl = node < n ? node : 0;                                             \
        _Pragma("unroll")                                                          \
        for (int kk = 0; kk < KK; ++kk) {                                          \
            int k = kk * 32 + kseg * 8;                                            \
            const unsigned short* p = (k < DIN) ? (Ab + (size_t)ncl * DIN + k)     \
                                                : (Fb + (size_t)ncl * DIN + (k - DIN)); \
            dst[kk] = *reinterpret_cast<const bf16x8*>(p);                         \
        }                                                                          \
    }

    #define COMPUTE(g, ab)                                                         \
    {                                                                              \
        f32x4 acc0 = {0.f, 0.f, 0.f, 0.f}, acc1 = {0.f, 0.f, 0.f, 0.f};           \
        _Pragma("unroll")                                                          \
        for (int kk = 0; kk < KK; ++kk) {                                          \
            acc0 = __builtin_amdgcn_mfma_f32_16x16x32_bf16(ab[kk], b0[kk], acc0, 0, 0, 0); \
            acc1 = __builtin_amdgcn_mfma_f32_16x16x32_bf16(ab[kk], b1[kk], acc1, 0, 0, 0); \
        }                                                                          \
        int gbase = (g0 + (g)) * 16 + kseg * 4;                                    \
        _Pragma("unroll")                                                          \
        for (int r = 0; r < 4; ++r) {                                              \
            int gn = gbase + r;                                                    \
            if (gn < n) {                                                          \
                int col0 = wc * 32 + arow;                                         \
                float v0 = fmaxf(acc0[r] + bv0, 0.f);                              \
                float v1 = fmaxf(acc1[r] + bv1, 0.f);                              \
                out[(size_t)gn * outs + col0] = v0;                                \
                out[(size_t)gn * outs + col0 + 16] = v1;                           \
                if constexpr (WB) {                                                \
                    outb[(size_t)gn * DOUT + col0] = f2bf(v0);                     \
                    outb[(size_t)gn * DOUT + col0 + 16] = f2bf(v1);                \
                }                                                                  \
            }                                                                      \
        }                                                                          \
    }

    LOADA(0, a0);
    #pragma unroll
    for (int gp = 0; gp < GW; gp += 2) {
        LOADA(gp + 1, a1);
        COMPUTE(gp, a0);
        if (gp + 2 < GW) LOADA(gp + 2, a0);
        COMPUTE(gp + 1, a1);
    }
    #undef LOADA
    #undef COMPUTE
}

extern "C" void kernel_launch(void* const* d_in, const int* in_sizes, int n_in,
                              void* d_out, int out_size, void* d_ws, size_t ws_size,
                              hipStream_t stream) {
    const float* x   = (const float*)d_in[0];
    const int*   ei  = (const int*)d_in[1];
    const float* W1l = (const float*)d_in[2];
    const float* b1  = (const float*)d_in[3];
    const float* W1r = (const float*)d_in[4];
    const float* W2l = (const float*)d_in[5];
    const float* b2  = (const float*)d_in[6];
    const float* W2r = (const float*)d_in[7];
    const float* W3l = (const float*)d_in[8];
    const float* b3  = (const float*)d_in[9];
    const float* W3r = (const float*)d_in[10];
    float* out = (float*)d_out;

    const int* src = ei;
    const int* dst = ei + N_EDGES;

    int* wsi = (int*)d_ws;
    int*   cnt      = wsi;                    // NP
    int*   total    = wsi + NP;               // 64
    int*   row_ptr  = wsi + NP + 64;          // NP
    float* inv_deg  = (float*)(wsi + 2 * NP + 64);
    int*   edge_src = wsi + 3 * NP + 64;      // E
    int*   pos      = edge_src + N_EDGES;     // E
    unsigned short* Wc1 = (unsigned short*)(pos + N_EDGES);       // 128*256
    unsigned short* Wc2 = Wc1 + 128 * 256;                        // 64*256
    unsigned short* Wc3 = Wc2 + 64 * 256;                         // 128*128
    unsigned short* meanb = Wc3 + 128 * 128;                      // N*128 bf16
    unsigned short* xb  = meanb + (size_t)N_NODES * 128;          // N*128 bf16
    unsigned short* h1b = xb + (size_t)N_NODES * 128;             // N*128 bf16
    unsigned short* h2b = h1b + (size_t)N_NODES * 128;            // N*64  bf16

    zero_kernel<<<(NP + 64 + 255) / 256, 256, 0, stream>>>(cnt, NP + 64);

    prep_kernel<<<EB4 + WCB + CVB, 256, 0, stream>>>(dst, cnt, pos,
        W1l, W1r, W2l, W2r, W3l, W3r, Wc1, Wc2, Wc3, x, xb);

    assign_kernel<<<NP / 256, 256, 0, stream>>>(cnt, row_ptr, inv_deg, total, N_NODES);
    fill_kernel<<<EB4, 256, 0, stream>>>(src, dst, row_ptr, pos, edge_src);

    const int AGG_BLOCKS = (N_NODES + 3) / 4;
    const int GB64  = (N_NODES + 63) / 64;     // 782
    const int GB128 = (N_NODES + 127) / 128;   // 391

    // layer 1
    agg_kernel<128><<<AGG_BLOCKS, 256, 0, stream>>>(xb, row_ptr, cnt, edge_src, inv_deg, meanb, N_NODES);
    mfma_gemm_kernel<256, 128, true><<<GB64, 256, 0, stream>>>(meanb, xb, Wc1, b1, out, 320, h1b, N_NODES);

    // layer 2
    agg_kernel<128><<<AGG_BLOCKS, 256, 0, stream>>>(h1b, row_ptr, cnt, edge_src, inv_deg, meanb, N_NODES);
    mfma_gemm_kernel<256, 64, true><<<GB128, 256, 0, stream>>>(meanb, h1b, Wc2, b2, out + 128, 320, h2b, N_NODES);

    // layer 3
    agg_kernel<64><<<AGG_BLOCKS, 256, 0, stream>>>(h2b, row_ptr, cnt, edge_src, inv_deg, meanb, N_NODES);
    mfma_gemm_kernel<128, 128, false><<<GB64, 256, 0, stream>>>(meanb, h2b, Wc3, b3, out + 192, 320, nullptr, N_NODES);
}